// Round 2
// baseline (95.219 us; speedup 1.0000x reference)
//
#include <hip/hip_runtime.h>

// Fused additive-window-attention, B=256, L=75, U=64, W=16 window, all f32.
// One block per batch. Phase 1: Q=X Wt^T, K=X Wx^T into LDS (waves 0-3 -> Q,
// waves 4-7 -> K; weight row per lane in 16 float4 VGPRs). Phase 2: exact
// windowed softmax (out-of-window exp underflows to 0 in f32) + PV from LDS.
static constexpr int LSEQ = 75;
static constexpr int UDIM = 64;
static constexpr int QK_STRIDE = 68;  // +4 pad: phase-2 b128 reads <=2-way/quarter-wave

// tanh(x) = copysign((1-z)/(1+z), x), z = exp(-2|x|) in (0,1] -> no overflow.
__device__ __forceinline__ float fast_tanh(float x) {
    float ax = fabsf(x);
    float z  = __expf(-2.0f * ax);
    float t  = (1.0f - z) * __builtin_amdgcn_rcpf(1.0f + z);
    return copysignf(t, x);
}

__global__ __launch_bounds__(512) void fused_attn_kernel(
    const float* __restrict__ X,     // [B,L,U]
    const float* __restrict__ Wt,    // [U,U] (row v = weights for output v)
    const float* __restrict__ Wx,    // [U,U]
    const float* __restrict__ bh,    // [U]
    const float* __restrict__ Wa,    // [1,U]
    const float* __restrict__ rel,   // [2L-1,U]
    float* __restrict__ out)         // [B,L,U]
{
    __shared__ float x_s[LSEQ][UDIM];        // 19200 B
    __shared__ float q_s[LSEQ][QK_STRIDE];   // 20400 B
    __shared__ float k_s[LSEQ][QK_STRIDE];   // 20400 B  (total 60000 B)

    const int tid  = threadIdx.x;
    const int lane = tid & 63;
    const int wave = tid >> 6;       // 0..7
    const int b    = blockIdx.x;

    // ---- Stage X[b] (4800 floats = 1200 float4, coalesced) ----
    const float* xb = X + (long)b * (LSEQ * UDIM);
    for (int i = tid; i < LSEQ * UDIM / 4; i += 512)
        ((float4*)x_s)[i] = ((const float4*)xb)[i];

    // ---- Weight row for this lane, in registers (64 VGPRs, phase-1 only) ----
    const float* wrow = ((wave < 4) ? Wt : Wx) + lane * UDIM;
    float4 wreg[16];
    #pragma unroll
    for (int c = 0; c < 16; ++c) wreg[c] = ((const float4*)wrow)[c];

    __syncthreads();

    // ---- Phase 1: GEMM. waves 0-3: Q rows r%4==wave; waves 4-7: K rows. ----
    {
        float* dst = (wave < 4) ? &q_s[0][0] : &k_s[0][0];
        const int w4 = wave & 3;
        for (int r = w4; r < LSEQ; r += 4) {
            float acc = 0.f;
            #pragma unroll
            for (int c = 0; c < 16; ++c) {
                float4 xv = *(const float4*)(&x_s[r][c * 4]);  // wave-broadcast
                acc = fmaf(xv.x, wreg[c].x, acc);
                acc = fmaf(xv.y, wreg[c].y, acc);
                acc = fmaf(xv.z, wreg[c].z, acc);
                acc = fmaf(xv.w, wreg[c].w, acc);
            }
            dst[r * QK_STRIDE + lane] = acc;  // consecutive lanes -> conflict-free
        }
    }

    // ---- Per-lane constants for phase 2: lane = w*4 + s ----
    const int w  = lane >> 2;        // window pos 0..15 (kk = j-8+w)
    const int s  = lane & 3;         // u-chunk 0..3
    const int u0 = s * 16;
    float4 rb[4], wa4[4];
    {
        const float* relrow = rel + (82 - w) * UDIM + u0;  // j-independent
        #pragma unroll
        for (int c = 0; c < 4; ++c) {
            float4 r4 = *(const float4*)(relrow + c * 4);
            float4 b4 = *(const float4*)(bh + u0 + c * 4);
            rb[c]  = make_float4(r4.x + b4.x, r4.y + b4.y, r4.z + b4.z, r4.w + b4.w);
            wa4[c] = *(const float4*)(Wa + u0 + c * 4);
        }
    }

    __syncthreads();

    // ---- Phase 2: windowed attention; wave handles rows j = wave, wave+8, ... ----
    for (int j = wave; j < LSEQ; j += 8) {
        const int  kk    = j - 8 + w;
        const bool valid = (kk >= 0) && (kk < LSEQ);
        const int  kks   = valid ? kk : j;   // safe LDS row for invalid lanes

        float pd = 0.f;
        #pragma unroll
        for (int c = 0; c < 4; ++c) {
            float4 q4 = *(const float4*)(&q_s[j][u0 + c * 4]);
            float4 k4 = *(const float4*)(&k_s[kks][u0 + c * 4]);
            pd = fmaf(fast_tanh(q4.x + k4.x + rb[c].x), wa4[c].x, pd);
            pd = fmaf(fast_tanh(q4.y + k4.y + rb[c].y), wa4[c].y, pd);
            pd = fmaf(fast_tanh(q4.z + k4.z + rb[c].z), wa4[c].z, pd);
            pd = fmaf(fast_tanh(q4.w + k4.w + rb[c].w), wa4[c].w, pd);
        }
        // e_w: sum the 4 u-chunks (lane bits 0..1).
        pd += __shfl_xor(pd, 1);
        pd += __shfl_xor(pd, 2);
        float e = valid ? pd : -1e30f;

        // softmax across w (lane bits 2..5).
        float m = e;
        m = fmaxf(m, __shfl_xor(m, 4));
        m = fmaxf(m, __shfl_xor(m, 8));
        m = fmaxf(m, __shfl_xor(m, 16));
        m = fmaxf(m, __shfl_xor(m, 32));
        float p = valid ? __expf(e - m) : 0.f;
        float sum = p;
        sum += __shfl_xor(sum, 4);
        sum += __shfl_xor(sum, 8);
        sum += __shfl_xor(sum, 16);
        sum += __shfl_xor(sum, 32);
        const float a = p * __builtin_amdgcn_rcpf(sum);  // sum >= 1

        // PV: lane -> u; a_w broadcast from lane 4*ww; x_s row reads conflict-free.
        const int wlo = (j < 8) ? (8 - j) : 0;
        const int whi = (LSEQ + 8 - j < 16) ? (LSEQ + 8 - j) : 16;
        float acc = 0.f;
        for (int ww = wlo; ww < whi; ++ww) {
            float aw = __shfl(a, ww * 4);
            acc = fmaf(aw, x_s[j - 8 + ww][lane], acc);
        }
        out[((long)(b * LSEQ + j)) * UDIM + lane] = acc;
    }
}

extern "C" void kernel_launch(void* const* d_in, const int* in_sizes, int n_in,
                              void* d_out, int out_size, void* d_ws, size_t ws_size,
                              hipStream_t stream)
{
    const float* X   = (const float*)d_in[0];  // [B,L,U] f32
    const float* Wt  = (const float*)d_in[1];  // [U,U]
    const float* Wx  = (const float*)d_in[2];  // [U,U]
    const float* bh  = (const float*)d_in[3];  // [U]
    const float* Wa  = (const float*)d_in[4];  // [1,U]
    // d_in[5] = ba: uniform over the softmax axis -> cancels, unused.
    const float* rel = (const float*)d_in[6];  // [2L-1,U]
    float* out = (float*)d_out;                // [B,L,U] f32

    fused_attn_kernel<<<256, 512, 0, stream>>>(X, Wt, Wx, bh, Wa, rel, out);
}

// Round 3
// 89.330 us; speedup vs baseline: 1.0659x; 1.0659x over previous
//
#include <hip/hip_runtime.h>

// Fused additive-window-attention, B=256, L=75, U=64, W=16 window, all f32.
// One block (1024 thr = 16 waves) per batch: 4 waves/SIMD for latency hiding.
// Phase 1: Q=X Wt^T (waves 0-7), K=X Wx^T (waves 8-15) into LDS; weight row
// per lane held in 16 float4 VGPRs. Phase 2: exact windowed softmax
// (out-of-window exp underflows to 0 in f32; max-subtraction dropped since
// |e| <= sum|Wa| ~ 9 cannot overflow) + fully-unrolled PV.
static constexpr int LSEQ = 75;
static constexpr int UDIM = 64;
static constexpr int QK_STRIDE = 68;  // +4 pad for phase-2 b128 reads

// tanh(x) = copysign((1-z)/(1+z), x), z = exp(-2|x|) in (0,1] -> no overflow.
__device__ __forceinline__ float fast_tanh(float x) {
    float ax = fabsf(x);
    float z  = __expf(-2.0f * ax);
    float t  = (1.0f - z) * __builtin_amdgcn_rcpf(1.0f + z);
    return copysignf(t, x);
}

__global__ __launch_bounds__(1024, 4) void fused_attn_kernel(
    const float* __restrict__ X,     // [B,L,U]
    const float* __restrict__ Wt,    // [U,U]
    const float* __restrict__ Wx,    // [U,U]
    const float* __restrict__ bh,    // [U]
    const float* __restrict__ Wa,    // [1,U]
    const float* __restrict__ rel,   // [2L-1,U]
    float* __restrict__ out)         // [B,L,U]
{
    __shared__ float x_s[LSEQ][UDIM];        // 19200 B
    __shared__ float q_s[LSEQ][QK_STRIDE];   // 20400 B
    __shared__ float k_s[LSEQ][QK_STRIDE];   // 20400 B  (total 60000 B)

    const int tid  = threadIdx.x;
    const int lane = tid & 63;
    const int wave = tid >> 6;       // 0..15
    const int b    = blockIdx.x;

    // ---- Stage X[b] (1200 float4, coalesced) ----
    const float* xb = X + (long)b * (LSEQ * UDIM);
    for (int i = tid; i < LSEQ * UDIM / 4; i += 1024)
        ((float4*)x_s)[i] = ((const float4*)xb)[i];

    // ---- Weight row for this lane in registers (64 VGPRs, phase-1 only) ----
    const int isK = wave >> 3;                       // 0: Q-wave, 1: K-wave
    const float* wrow = (isK ? Wx : Wt) + lane * UDIM;
    float4 wreg[16];
    #pragma unroll
    for (int c = 0; c < 16; ++c) wreg[c] = ((const float4*)wrow)[c];

    __syncthreads();

    // ---- Phase 1: GEMM. wave w: rows r = (w&7), (w&7)+8, ... ----
    {
        float* dst = isK ? &k_s[0][0] : &q_s[0][0];
        const int w8 = wave & 7;
        for (int r = w8; r < LSEQ; r += 8) {
            float acc = 0.f;
            #pragma unroll
            for (int c = 0; c < 16; ++c) {
                float4 xv = *(const float4*)(&x_s[r][c * 4]);  // wave-broadcast
                acc = fmaf(xv.x, wreg[c].x, acc);
                acc = fmaf(xv.y, wreg[c].y, acc);
                acc = fmaf(xv.z, wreg[c].z, acc);
                acc = fmaf(xv.w, wreg[c].w, acc);
            }
            dst[r * QK_STRIDE + lane] = acc;  // consecutive lanes, conflict-free
        }
    }

    // ---- Per-lane constants for phase 2: lane = w*4 + s ----
    const int w  = lane >> 2;        // window pos 0..15 (kk = j-8+w)
    const int s  = lane & 3;         // u-chunk 0..3
    const int u0 = s * 16;
    float4 rb[4], wa4[4];
    {
        const float* relrow = rel + (82 - w) * UDIM + u0;  // j-independent
        #pragma unroll
        for (int c = 0; c < 4; ++c) {
            float4 r4 = *(const float4*)(relrow + c * 4);
            float4 b4 = *(const float4*)(bh + u0 + c * 4);
            rb[c]  = make_float4(r4.x + b4.x, r4.y + b4.y, r4.z + b4.z, r4.w + b4.w);
            wa4[c] = *(const float4*)(Wa + u0 + c * 4);
        }
    }

    __syncthreads();

    // ---- Phase 2: wave handles rows j = wave, wave+16, ... ----
    for (int j = wave; j < LSEQ; j += 16) {
        const int  kk    = j - 8 + w;
        const bool valid = (kk >= 0) && (kk < LSEQ);
        const int  kks   = valid ? kk : j;   // safe LDS row (value masked later)

        float pd = 0.f;
        #pragma unroll
        for (int c = 0; c < 4; ++c) {
            float4 q4 = *(const float4*)(&q_s[j][u0 + c * 4]);
            float4 k4 = *(const float4*)(&k_s[kks][u0 + c * 4]);
            pd = fmaf(fast_tanh(q4.x + k4.x + rb[c].x), wa4[c].x, pd);
            pd = fmaf(fast_tanh(q4.y + k4.y + rb[c].y), wa4[c].y, pd);
            pd = fmaf(fast_tanh(q4.z + k4.z + rb[c].z), wa4[c].z, pd);
            pd = fmaf(fast_tanh(q4.w + k4.w + rb[c].w), wa4[c].w, pd);
        }
        // e_w: sum the 4 u-chunks (lane bits 0..1).
        pd += __shfl_xor(pd, 1);
        pd += __shfl_xor(pd, 2);

        // No-max softmax: |e| <= sum|Wa| ~ 9, exp cannot overflow; invalid
        // lanes get e = -1e30 -> exp underflows to exactly 0.
        float p = __expf(valid ? pd : -1e30f);
        float sum = p;
        sum += __shfl_xor(sum, 4);
        sum += __shfl_xor(sum, 8);
        sum += __shfl_xor(sum, 16);
        sum += __shfl_xor(sum, 32);
        const float a = p * __builtin_amdgcn_rcpf(sum);  // a = 0 for invalid w

        // PV: fixed-trip unrolled; aw = 0 for invalid ww, row clamped (masked).
        float acc = 0.f;
        #pragma unroll
        for (int ww = 0; ww < 16; ++ww) {
            float aw = __shfl(a, ww * 4);
            int row = j - 8 + ww;
            row = row < 0 ? 0 : (row > LSEQ - 1 ? LSEQ - 1 : row);
            acc = fmaf(aw, x_s[row][lane], acc);
        }
        out[((long)(b * LSEQ + j)) * UDIM + lane] = acc;
    }
}

extern "C" void kernel_launch(void* const* d_in, const int* in_sizes, int n_in,
                              void* d_out, int out_size, void* d_ws, size_t ws_size,
                              hipStream_t stream)
{
    const float* X   = (const float*)d_in[0];  // [B,L,U] f32
    const float* Wt  = (const float*)d_in[1];  // [U,U]
    const float* Wx  = (const float*)d_in[2];  // [U,U]
    const float* bh  = (const float*)d_in[3];  // [U]
    const float* Wa  = (const float*)d_in[4];  // [1,U]
    // d_in[5] = ba: uniform over the softmax axis -> cancels, unused.
    const float* rel = (const float*)d_in[6];  // [2L-1,U]
    float* out = (float*)d_out;                // [B,L,U] f32

    fused_attn_kernel<<<256, 1024, 0, stream>>>(X, Wt, Wx, bh, Wa, rel, out);
}

// Round 4
// 87.496 us; speedup vs baseline: 1.0883x; 1.0210x over previous
//
#include <hip/hip_runtime.h>

// Fused additive-window-attention, B=256, L=75, U=64, W=16 window, all f32.
// One block (1024 thr = 16 waves) per batch. Phase 1: Q=X Wt^T (waves 0-7),
// K=X Wx^T (waves 8-15) into LDS via packed v_pk_fma_f32 (2x f32 rate).
// Phase 2: exact windowed softmax (out-of-window exp underflows to 0 in f32;
// max-subtraction dropped since |e| <= sum|Wa| ~ 9), two j-rows in flight
// per wave for ILP, fully-unrolled PV.
static constexpr int LSEQ = 75;
static constexpr int UDIM = 64;
static constexpr int QK_STRIDE = 68;  // +4 pad for phase-2 b128 reads

typedef __attribute__((ext_vector_type(2))) float f32x2;

// tanh(x) = copysign((1-z)/(1+z), x), z = exp(-2|x|) in (0,1] -> no overflow.
__device__ __forceinline__ float fast_tanh(float x) {
    float ax = fabsf(x);
    float z  = __expf(-2.0f * ax);
    float t  = (1.0f - z) * __builtin_amdgcn_rcpf(1.0f + z);
    return copysignf(t, x);
}

__global__ __launch_bounds__(1024, 4) void fused_attn_kernel(
    const float* __restrict__ X,     // [B,L,U]
    const float* __restrict__ Wt,    // [U,U]
    const float* __restrict__ Wx,    // [U,U]
    const float* __restrict__ bh,    // [U]
    const float* __restrict__ Wa,    // [1,U]
    const float* __restrict__ rel,   // [2L-1,U]
    float* __restrict__ out)         // [B,L,U]
{
    __shared__ float x_s[LSEQ][UDIM];        // 19200 B
    __shared__ float q_s[LSEQ][QK_STRIDE];   // 20400 B
    __shared__ float k_s[LSEQ][QK_STRIDE];   // 20400 B  (total 60000 B)

    const int tid  = threadIdx.x;
    const int lane = tid & 63;
    const int wave = tid >> 6;       // 0..15
    const int b    = blockIdx.x;

    // ---- Stage X[b] (1200 float4, coalesced) ----
    const float* xb = X + (long)b * (LSEQ * UDIM);
    for (int i = tid; i < LSEQ * UDIM / 4; i += 1024)
        ((float4*)x_s)[i] = ((const float4*)xb)[i];

    // ---- Weight row for this lane in registers as f32x2 pairs (64 VGPRs) ----
    const int isK = wave >> 3;                       // 0: Q-wave, 1: K-wave
    const f32x2* wrow2 = (const f32x2*)(((isK ? Wx : Wt) + lane * UDIM));
    f32x2 wreg2[32];
    #pragma unroll
    for (int c = 0; c < 32; ++c) wreg2[c] = wrow2[c];

    __syncthreads();

    // ---- Phase 1: GEMM via v_pk_fma_f32, two packed accumulators. ----
    {
        float* dst = isK ? &k_s[0][0] : &q_s[0][0];
        const int w8 = wave & 7;
        for (int r = w8; r < LSEQ; r += 8) {
            const f32x2* xr = (const f32x2*)&x_s[r][0];  // wave-broadcast reads
            f32x2 accA = {0.f, 0.f}, accB = {0.f, 0.f};
            #pragma unroll
            for (int c = 0; c < 32; c += 2) {
                f32x2 xa = xr[c];
                f32x2 xc = xr[c + 1];
                asm("v_pk_fma_f32 %0, %1, %2, %0" : "+v"(accA) : "v"(xa), "v"(wreg2[c]));
                asm("v_pk_fma_f32 %0, %1, %2, %0" : "+v"(accB) : "v"(xc), "v"(wreg2[c + 1]));
            }
            dst[r * QK_STRIDE + lane] = (accA.x + accA.y) + (accB.x + accB.y);
        }
    }

    // ---- Per-lane constants for phase 2: lane = w*4 + s ----
    const int w  = lane >> 2;        // window pos 0..15 (kk = j-8+w)
    const int s  = lane & 3;         // u-chunk 0..3
    const int u0 = s * 16;
    float4 rb[4], wa4[4];
    {
        const float* relrow = rel + (82 - w) * UDIM + u0;  // j-independent
        #pragma unroll
        for (int c = 0; c < 4; ++c) {
            float4 r4 = *(const float4*)(relrow + c * 4);
            float4 b4 = *(const float4*)(bh + u0 + c * 4);
            rb[c]  = make_float4(r4.x + b4.x, r4.y + b4.y, r4.z + b4.z, r4.w + b4.w);
            wa4[c] = *(const float4*)(Wa + u0 + c * 4);
        }
    }

    __syncthreads();

    // ---- Phase 2: two j-rows in flight per wave (j0 and j0+16). ----
    for (int j0 = wave; j0 < LSEQ; j0 += 32) {
        #pragma unroll
        for (int r = 0; r < 2; ++r) {            // static unroll -> interleaved ILP
            const int j = j0 + r * 16;
            if (j >= LSEQ) continue;             // wave-uniform guard
            const int  kk    = j - 8 + w;
            const bool valid = (kk >= 0) && (kk < LSEQ);
            const int  kks   = valid ? kk : j;   // safe LDS row (masked later)

            float pd = 0.f;
            #pragma unroll
            for (int c = 0; c < 4; ++c) {
                float4 q4 = *(const float4*)(&q_s[j][u0 + c * 4]);
                float4 k4 = *(const float4*)(&k_s[kks][u0 + c * 4]);
                pd = fmaf(fast_tanh(q4.x + k4.x + rb[c].x), wa4[c].x, pd);
                pd = fmaf(fast_tanh(q4.y + k4.y + rb[c].y), wa4[c].y, pd);
                pd = fmaf(fast_tanh(q4.z + k4.z + rb[c].z), wa4[c].z, pd);
                pd = fmaf(fast_tanh(q4.w + k4.w + rb[c].w), wa4[c].w, pd);
            }
            // e_w: sum the 4 u-chunks (lane bits 0..1).
            pd += __shfl_xor(pd, 1);
            pd += __shfl_xor(pd, 2);

            // No-max softmax: |e| <= sum|Wa| ~ 9, exp cannot overflow; invalid
            // lanes get e = -1e30 -> exp underflows to exactly 0.
            float p = __expf(valid ? pd : -1e30f);
            float sum = p;
            sum += __shfl_xor(sum, 4);
            sum += __shfl_xor(sum, 8);
            sum += __shfl_xor(sum, 16);
            sum += __shfl_xor(sum, 32);
            const float a = p * __builtin_amdgcn_rcpf(sum);  // 0 for invalid w

            // PV: lane -> u; a_w broadcast from lane 4*ww; rows clamped+masked.
            float accE = 0.f, accO = 0.f;        // 2 accumulators for ILP
            #pragma unroll
            for (int ww = 0; ww < 16; ww += 2) {
                float aw0 = __shfl(a, ww * 4);
                float aw1 = __shfl(a, ww * 4 + 4);
                int r0 = j - 8 + ww;
                int r1 = r0 + 1;
                r0 = r0 < 0 ? 0 : (r0 > LSEQ - 1 ? LSEQ - 1 : r0);
                r1 = r1 < 0 ? 0 : (r1 > LSEQ - 1 ? LSEQ - 1 : r1);
                accE = fmaf(aw0, x_s[r0][lane], accE);
                accO = fmaf(aw1, x_s[r1][lane], accO);
            }
            out[((long)(b * LSEQ + j)) * UDIM + lane] = accE + accO;
        }
    }
}

extern "C" void kernel_launch(void* const* d_in, const int* in_sizes, int n_in,
                              void* d_out, int out_size, void* d_ws, size_t ws_size,
                              hipStream_t stream)
{
    const float* X   = (const float*)d_in[0];  // [B,L,U] f32
    const float* Wt  = (const float*)d_in[1];  // [U,U]
    const float* Wx  = (const float*)d_in[2];  // [U,U]
    const float* bh  = (const float*)d_in[3];  // [U]
    const float* Wa  = (const float*)d_in[4];  // [1,U]
    // d_in[5] = ba: uniform over the softmax axis -> cancels, unused.
    const float* rel = (const float*)d_in[6];  // [2L-1,U]
    float* out = (float*)d_out;                // [B,L,U] f32

    fused_attn_kernel<<<256, 1024, 0, stream>>>(X, Wt, Wx, bh, Wa, rel, out);
}